// Round 10
// baseline (134.229 us; speedup 1.0000x reference)
//
#include <hip/hip_runtime.h>
#include <hip/hip_bf16.h>

// LSTM_71382356459716 R9: trans-pipe + LDS-pipe trim package.
// Model after R8: wall ~57us tracks trans-instruction count weakly across
// R1/R6/R8 -> trans unit is execution-occupancy-bound (~25-30cyc/wave64
// trans, VALUBusy counts issue only). Cuts:
//  (1) exp2 prescale: prep kernel scales gate rows by log2(e) (i,f,o) and
//      2*log2(e) (g); c_state carried in 2*log2(e)-scaled units. Every
//      __expf(-x) (v_mul+v_exp) becomes bare v_exp_f32: -5 muls/tuple.
//  (2) rcp grouping {i,f,g} + {o,c}: 8 -> 7 trans per tuple.
//  (3) h-store = ONE ds_write_b64/lane: LDS h-ordering re-permuted (sigma
//      baked into prep's W_hh columns and the FC index) so a lane's 4 h
//      values are contiguous. -3 LDS write instrs, -4 shifts per lane/step.
// Kept: 1024 blocks x 4 waves, 16 rows/block, 4 M-tiles stationary per wave
// (A from 48KB frag-ordered ws, 12 coalesced b128 loads), bias folded into
// W col 28 vs constant-1 x col, balanced stagers, two-deep x prefetch,
// double-buffered LDS rows of 104 shorts, 3 ds_read_b128 B-frags, 1 barrier.

namespace {
constexpr int B_TOT   = 16384;
constexpr int T_STEPS = 28;
constexpr int IN_DIM  = 28;
constexpr int HID     = 64;
constexpr int OUT_DIM = 10;
constexpr int ROWS    = 16;    // batch rows per block -> 1024 blocks, 4/CU
constexpr int THREADS = 256;   // 4 waves
constexpr int KP      = 104;   // row stride in shorts (208 B, odd*16B)
constexpr int XROW    = T_STEPS * IN_DIM;  // 784 floats per batch row
constexpr int WS_ELEMS = 48 * 64 * 8;      // 24576 bf16 = 48 KB
}

typedef __attribute__((ext_vector_type(8))) short short8v;   // 8 bf16
typedef __attribute__((ext_vector_type(4))) short short4v;
typedef __attribute__((ext_vector_type(4))) float float4v;

__device__ __forceinline__ short f2bf_cold(float f) {
  union { float f; unsigned u; } v; v.f = f;
  unsigned r = v.u + 0x7FFFu + ((v.u >> 16) & 1u);
  return (short)(r >> 16);
}
__device__ __forceinline__ float bf2f(short s) {
  union { unsigned u; float f; } v; v.u = ((unsigned)(unsigned short)s) << 16;
  return v.f;
}
__device__ __forceinline__ unsigned pk2(float a, float b) {  // 2xf32->bf16x2
  __hip_bfloat162 h = __float22bfloat162_rn(float2{a, b});
  union { __hip_bfloat162 h; unsigned u; } cv; cv.h = h; return cv.u;
}

// ---- setup: permute+prescale weights into MFMA A-frag order ----------------
// Frag f = mt*3 + kc, lane l, elem j:
//   ws[(f*64+l)*8+j] = bf16( scale(type) * Araw[m=16*mt+(l&15)][k=kc*32+(l>>4)*8+j] )
// gate row g = (m&3)*64 + (m>>2); scale = log2e (types i,f,o) / 2*log2e (g).
// k<28 -> W_ih; k==28 -> b_ih+b_hh; 29..31 -> 0;
// k>=32 -> W_hh column through sigma^-1: p=k-32, u = 16*(p>>4)+4*(p&3)+((p>>2)&3)
// (so that lane (w,q)'s 4 h-outputs {i=0..3} land contiguously at 16w+4q+i).
__global__ void lstm_prep(const float* __restrict__ W_ih,
                          const float* __restrict__ W_hh,
                          const float* __restrict__ b_ih,
                          const float* __restrict__ b_hh,
                          unsigned short* __restrict__ ws) {
  int idx = blockIdx.x * blockDim.x + threadIdx.x;
  if (idx >= WS_ELEMS) return;
  int j  = idx & 7;
  int l  = (idx >> 3) & 63;
  int fk = idx >> 9;            // mt*3 + kc
  int kc = fk % 3;
  int mt = fk / 3;
  int m  = 16 * mt + (l & 15);
  int unit = m >> 2, type = m & 3;
  int g  = type * 64 + unit;
  int k  = kc * 32 + (l >> 4) * 8 + j;
  float v = 0.0f;
  if (k < IN_DIM)        v = W_ih[g * IN_DIM + k];
  else if (k == IN_DIM)  v = b_ih[g] + b_hh[g];
  else if (k >= 32) {
    int p = k - 32;
    int u = 16 * (p >> 4) + 4 * (p & 3) + ((p >> 2) & 3);
    v = W_hh[g * HID + u];
  }
  v *= (type == 2) ? 2.8853900817779268f : 1.4426950408889634f;
  ws[idx] = (unsigned short)f2bf_cold(v);
}

__global__ __attribute__((amdgpu_flat_work_group_size(THREADS, THREADS),
                          amdgpu_waves_per_eu(4, 4)))
void lstm_mfma9(const float* __restrict__ x,
                const unsigned short* __restrict__ wfrag,
                const float* __restrict__ W_fc,
                const float* __restrict__ b_fc, float* __restrict__ out) {
  __shared__ short hs[2][ROWS][KP];   // [buf][row][k]: 0..27 x, 28=1.0, 32..95 h(perm)

  const int tid  = threadIdx.x;
  const int lane = tid & 63;
  const int w    = tid >> 6;      // wave 0..3
  const int l15  = lane & 15;
  const int q    = lane >> 4;     // 0..3
  const int b0   = blockIdx.x * ROWS;

  // ---- stationary A: 12 coalesced 16B loads per lane -----------------------
  short8v a[4][3];
#pragma unroll
  for (int i = 0; i < 4; ++i)
#pragma unroll
    for (int kc = 0; kc < 3; ++kc)
      a[i][kc] = *(const short8v*)&wfrag[((((4 * w + i) * 3) + kc) * 64 + lane) * 8];

  // zero both buffers, then set the constant bias column
  for (int idx = tid; idx < 2 * ROWS * KP; idx += THREADS) (&hs[0][0][0])[idx] = 0;
  __syncthreads();
  if (tid < 2 * ROWS) hs[tid >> 4][tid & 15][IN_DIM] = (short)0x3F80;  // bf16 1.0

  // ---- x staging balanced across waves: lanes 0..27 of each wave -----------
  const bool stager = (lane < 28);
  const int  s  = w * 28 + lane;
  const int  sr = s / 7;
  const int  sc = s - 7 * sr;
  const float* xptr = x + (size_t)(b0 + sr) * XROW + sc * 4;

  float4 xfly = {0.f, 0.f, 0.f, 0.f};
  if (stager) {
    float4 x0 = *(const float4*)xptr;
    short4v sv;
    unsigned plo = pk2(x0.x, x0.y), phi = pk2(x0.z, x0.w);
    sv[0] = (short)(plo & 0xFFFF); sv[1] = (short)(plo >> 16);
    sv[2] = (short)(phi & 0xFFFF); sv[3] = (short)(phi >> 16);
    *(short4v*)&hs[0][sr][sc * 4] = sv;
    xfly = *(const float4*)(xptr + 1 * IN_DIM);   // x_1, consumed at t=0
  }
  __syncthreads();

  float c_state[4] = {0.f, 0.f, 0.f, 0.f};   // in 2*log2e-scaled units

  for (int t = 0; t < T_STEPS; ++t) {
    const int cur = t & 1, nxt = cur ^ 1;

    // B-frags: lane holds B[k = kc*32 + q*8 + j][n = l15]
    short8v bf0 = *(const short8v*)&hs[cur][l15][q * 8];
    short8v bf1 = *(const short8v*)&hs[cur][l15][32 + q * 8];
    short8v bf2 = *(const short8v*)&hs[cur][l15][64 + q * 8];

    // store x_{t+1} (loaded a full step ago), issue load of x_{t+2}
    if (stager) {
      if (t + 1 < T_STEPS) {
        short4v sv;
        unsigned plo = pk2(xfly.x, xfly.y), phi = pk2(xfly.z, xfly.w);
        sv[0] = (short)(plo & 0xFFFF); sv[1] = (short)(plo >> 16);
        sv[2] = (short)(phi & 0xFFFF); sv[3] = (short)(phi >> 16);
        *(short4v*)&hs[nxt][sr][sc * 4] = sv;
      }
      if (t + 2 < T_STEPS)
        xfly = *(const float4*)(xptr + (t + 2) * IN_DIM);
    }

    const float4v zero4 = {0.f, 0.f, 0.f, 0.f};
    float4v acc[4];
#pragma unroll
    for (int i = 0; i < 4; ++i)
      acc[i] = __builtin_amdgcn_mfma_f32_16x16x32_bf16(a[i][0], bf0, zero4, 0, 0, 0);
#pragma unroll
    for (int i = 0; i < 4; ++i)
      acc[i] = __builtin_amdgcn_mfma_f32_16x16x32_bf16(a[i][1], bf1, acc[i], 0, 0, 0);
#pragma unroll
    for (int i = 0; i < 4; ++i)
      acc[i] = __builtin_amdgcn_mfma_f32_16x16x32_bf16(a[i][2], bf2, acc[i], 0, 0, 0);

    // activations: gates pre-scaled so sigma(v)=1/(1+exp2(-vhat)),
    // tanh(g)=(1-Eg)/(1+Eg) with Eg=exp2(-ghat). One rcp for {i,f,g},
    // one for {o, tanh(c)}. c in 2*log2e-scaled units.
    float hv[4];
#pragma unroll
    for (int i = 0; i < 4; ++i) {
      float4v g4 = acc[i];
      float Ei = __builtin_amdgcn_exp2f(-g4[0]);
      float Ef = __builtin_amdgcn_exp2f(-g4[1]);
      float Eg = __builtin_amdgcn_exp2f(-g4[2]);
      float di = 1.0f + Ei, df = 1.0f + Ef, dg = 1.0f + Eg;
      float t1 = di * df;
      float r1 = __builtin_amdgcn_rcpf(t1 * dg);
      float iv = r1 * (df * dg);
      float fv = r1 * (di * dg);
      // ghat_v = 2*log2e * tanh(g) = (r1*t1) * 2*log2e*(1-Eg)
      float gnum = fmaf(-Eg, 2.8853900817779268f, 2.8853900817779268f);
      float gv = (r1 * t1) * gnum;
      float cn = fmaf(fv, c_state[i], iv * gv);
      c_state[i] = cn;
      float ct = fminf(fmaxf(cn, -44.0f), 44.0f);   // keep exp2 finite
      float Eo = __builtin_amdgcn_exp2f(-g4[3]);
      float Ec = __builtin_amdgcn_exp2f(-ct);
      float dn = 1.0f + Eo, dc = 1.0f + Ec;
      float r2 = __builtin_amdgcn_rcpf(dn * dc);
      float ov = r2 * dc;                 // sigma(o)
      float tc = (r2 * dn) * (1.0f - Ec); // tanh(c)
      hv[i] = ov * tc;
    }
    // ONE b64 store: lane's units land at contiguous positions 16w+4q+0..3
    unsigned p01 = pk2(hv[0], hv[1]);
    unsigned p23 = pk2(hv[2], hv[3]);
    union { unsigned u[2]; short4v s; } pw;
    pw.u[0] = p01; pw.u[1] = p23;
    *(short4v*)&hs[nxt][l15][32 + 16 * w + 4 * q] = pw.s;

    __syncthreads();
  }

  // ---- FC epilogue: final h in hs[0], position p holds unit sigma^-1(p) ----
  if (tid < ROWS * OUT_DIM) {           // 160 outputs
    const int r = tid / OUT_DIM;
    const int o = tid - r * OUT_DIM;
    float sacc = b_fc[o];
#pragma unroll
    for (int p = 0; p < HID; ++p) {
      const int u = 16 * (p >> 4) + 4 * (p & 3) + ((p >> 2) & 3);
      sacc += bf2f(hs[0][r][32 + p]) * W_fc[o * HID + u];
    }
    out[(b0 + r) * OUT_DIM + o] = sacc;
  }
}

extern "C" void kernel_launch(void* const* d_in, const int* in_sizes, int n_in,
                              void* d_out, int out_size, void* d_ws, size_t ws_size,
                              hipStream_t stream) {
  const float* x    = (const float*)d_in[0];
  const float* W_ih = (const float*)d_in[1];
  const float* W_hh = (const float*)d_in[2];
  const float* b_ih = (const float*)d_in[3];
  const float* b_hh = (const float*)d_in[4];
  const float* W_fc = (const float*)d_in[5];
  const float* b_fc = (const float*)d_in[6];
  float* out = (float*)d_out;
  unsigned short* ws = (unsigned short*)d_ws;   // 48 KB frag-ordered weights

  lstm_prep<<<(WS_ELEMS + 255) / 256, 256, 0, stream>>>(W_ih, W_hh, b_ih, b_hh, ws);

  dim3 grid(B_TOT / ROWS);   // 1024 blocks -> 4 blocks/CU co-resident
  dim3 block(THREADS);
  lstm_mfma9<<<grid, block, 0, stream>>>(x, ws, W_fc, b_fc, out);
}